// Round 5
// baseline (7222.306 us; speedup 1.0000x reference)
//
#include <hip/hip_runtime.h>

typedef __bf16 bf16x8 __attribute__((ext_vector_type(8)));
typedef float f32x4 __attribute__((ext_vector_type(4)));

__device__ __forceinline__ unsigned short f2bf(float f) {
  unsigned u = __builtin_bit_cast(unsigned, f);
  u += 0x7fffu + ((u >> 16) & 1u);
  return (unsigned short)(u >> 16);
}
__device__ __forceinline__ float bf2f(unsigned short h) {
  unsigned u = ((unsigned)h) << 16;
  return __builtin_bit_cast(float, u);
}
__device__ __forceinline__ float sigmoidf_(float x) {
  return 1.f / (1.f + __expf(-x));
}
__device__ __forceinline__ float tanhf_(float x) {
  return 1.f - 2.f / (__expf(2.f * x) + 1.f);
}
// async global->LDS, 16B per lane. LDS dest must be wave-uniform base + lane*16.
__device__ __forceinline__ void gload16(const unsigned short* g, unsigned short* l) {
  __builtin_amdgcn_global_load_lds((const __attribute__((address_space(1))) void*)g,
                                   (__attribute__((address_space(3))) void*)l, 16, 0, 0);
}

// ---------- weight cast kernels ----------

__global__ __launch_bounds__(256) void k_castf(const float* __restrict__ src,
                                               unsigned short* __restrict__ dst, int n4) {
  int i = blockIdx.x * 256 + threadIdx.x;
  if (i < n4) {
    float4 v = ((const float4*)src)[i];
    ushort4 o;
    o.x = f2bf(v.x); o.y = f2bf(v.y); o.z = f2bf(v.z); o.w = f2bf(v.w);
    ((ushort4*)dst)[i] = o;
  }
}

// transpose-cast: src fp32 (K,N) row-major -> dst bf16 (Npad,K) row-major, zero-pad n>=N
__global__ void k_cast_t(const float* __restrict__ src, unsigned short* __restrict__ dst,
                         int K, int N) {
  __shared__ float tile[32][33];
  int nx = blockIdx.x * 32, ky = blockIdx.y * 32;
  int tx = threadIdx.x, ty = threadIdx.y; // 32 x 8
  #pragma unroll
  for (int j = 0; j < 32; j += 8) {
    int n = nx + tx, k = ky + ty + j;
    tile[ty + j][tx] = (n < N) ? src[(long)k * N + n] : 0.f;
  }
  __syncthreads();
  #pragma unroll
  for (int j = 0; j < 32; j += 8) {
    int n = nx + ty + j, k = ky + tx;
    dst[(long)n * K + k] = f2bf(tile[tx][ty + j]);
  }
}

// ---------- LayerNorm kernels ----------

// layer-0 LN with (B,T,F)->(T,B,F) transpose, F=128, fp32 in -> bf16 out
__global__ __launch_bounds__(128) void k_ln0(const float* __restrict__ x,
                                             unsigned short* __restrict__ out,
                                             const float* __restrict__ g,
                                             const float* __restrict__ be) {
  int row = blockIdx.x;            // t*16 + b
  int t = row >> 4, b = row & 15;
  const float* src = x + ((long)b * 1024 + t) * 128;
  int i = threadIdx.x;
  float v = src[i];
  float s = v, q = v * v;
  #pragma unroll
  for (int off = 32; off > 0; off >>= 1) {
    s += __shfl_down(s, off);
    q += __shfl_down(q, off);
  }
  __shared__ float red[4];
  int wv = i >> 6;
  if ((i & 63) == 0) { red[wv] = s; red[2 + wv] = q; }
  __syncthreads();
  float S = red[0] + red[1], Q = red[2] + red[3];
  float mean = S * (1.f / 128.f);
  float var = Q * (1.f / 128.f) - mean * mean;
  float rs = rsqrtf(var + 1e-5f);
  out[(long)row * 128 + i] = f2bf((v - mean) * rs * g[i] + be[i]);
}

// generic LN over C=1024 fp32 rows -> bf16 out16; avg=1 averages time-pairs
__global__ __launch_bounds__(256) void k_ln(const float* __restrict__ in,
                                            unsigned short* __restrict__ out16,
                                            const float* __restrict__ g,
                                            const float* __restrict__ be, int avg) {
  int row = blockIdx.x;
  int tid = threadIdx.x;
  int col = tid * 4;
  float xv[4];
  if (avg) {
    int l = row >> 4, b = row & 15;
    const float* r0 = in + ((long)(2 * l) * 16 + b) * 1024;
    const float* r1 = r0 + 16 * 1024;
    float4 a = *(const float4*)(r0 + col);
    float4 bb = *(const float4*)(r1 + col);
    xv[0] = 0.5f * (a.x + bb.x);
    xv[1] = 0.5f * (a.y + bb.y);
    xv[2] = 0.5f * (a.z + bb.z);
    xv[3] = 0.5f * (a.w + bb.w);
  } else {
    float4 a = *(const float4*)(in + (long)row * 1024 + col);
    xv[0] = a.x; xv[1] = a.y; xv[2] = a.z; xv[3] = a.w;
  }
  float s = xv[0] + xv[1] + xv[2] + xv[3];
  float q = xv[0]*xv[0] + xv[1]*xv[1] + xv[2]*xv[2] + xv[3]*xv[3];
  #pragma unroll
  for (int off = 32; off > 0; off >>= 1) {
    s += __shfl_down(s, off);
    q += __shfl_down(q, off);
  }
  __shared__ float red[8];
  int wv = tid >> 6;
  if ((tid & 63) == 0) { red[wv] = s; red[4 + wv] = q; }
  __syncthreads();
  float S = red[0] + red[1] + red[2] + red[3];
  float Q = red[4] + red[5] + red[6] + red[7];
  float mean = S * (1.f / 1024.f);
  float var = Q * (1.f / 1024.f) - mean * mean;
  float rs = rsqrtf(var + 1e-5f);
  ushort4 o;
  o.x = f2bf((xv[0] - mean) * rs * g[col + 0] + be[col + 0]);
  o.y = f2bf((xv[1] - mean) * rs * g[col + 1] + be[col + 1]);
  o.z = f2bf((xv[2] - mean) * rs * g[col + 2] + be[col + 2]);
  o.w = f2bf((xv[3] - mean) * rs * g[col + 3] + be[col + 3]);
  *(ushort4*)(out16 + (long)row * 1024 + col) = o;
}

// ---------- GEMM: A (M,K) bf16 x Bt (N,K) bf16 ----------
// 128x128 tile, BK=64, 4 waves (2x2), each wave 64x64 = 4x4 fragments of 16x16x32.
// Staging via global_load_lds width=16 (m97 structure).
// MODE 0: fp32 out (M,N). MODE 1: + bias1[n]+bias2[n], fp32 out.
// MODE 2: fp32 scatter to (B=16, L=512, 1001) with n<1001 mask.
// Requires M%128==0, N%128==0, K%64==0.
template <int MODE>
__global__ __launch_bounds__(256) void k_gemm(const unsigned short* __restrict__ A,
                                              const unsigned short* __restrict__ Bt,
                                              void* __restrict__ Cout,
                                              const float* __restrict__ bias1,
                                              const float* __restrict__ bias2,
                                              int M, int N, int K) {
  __shared__ unsigned short As[128][64]; // linear (unpadded) -- required by global_load_lds
  __shared__ unsigned short Bs[128][64];
  const int bn = blockIdx.x * 128, bm = blockIdx.y * 128;
  const int tid = threadIdx.x;
  const int wave = tid >> 6, lane = tid & 63;
  const int wm = (wave >> 1) * 64, wn = (wave & 1) * 64;
  const int l15 = lane & 15, kq = lane >> 4;
  f32x4 acc[4][4] = {};
  const int r0 = tid >> 3;
  const int c0 = (tid & 7) * 8;
  const unsigned short* Ap = A + (long)(bm + r0) * K + c0;
  const unsigned short* Bp = Bt + (long)(bn + r0) * K + c0;
  for (int kb = 0; kb < K; kb += 64) {
    #pragma unroll
    for (int i = 0; i < 4; i++) {
      gload16(Ap + (long)(i * 32) * K + kb, &As[i * 32 + r0][c0]);
      gload16(Bp + (long)(i * 32) * K + kb, &Bs[i * 32 + r0][c0]);
    }
    __syncthreads();
    #pragma unroll
    for (int kk = 0; kk < 2; kk++) {
      const int kcol = kk * 32 + kq * 8;
      bf16x8 a[4], b[4];
      #pragma unroll
      for (int m = 0; m < 4; m++) a[m] = *(const bf16x8*)&As[wm + m * 16 + l15][kcol];
      #pragma unroll
      for (int n = 0; n < 4; n++) b[n] = *(const bf16x8*)&Bs[wn + n * 16 + l15][kcol];
      #pragma unroll
      for (int m = 0; m < 4; m++)
        #pragma unroll
        for (int n = 0; n < 4; n++)
          acc[m][n] = __builtin_amdgcn_mfma_f32_16x16x32_bf16(a[m], b[n], acc[m][n], 0, 0, 0);
    }
    __syncthreads();
  }
  #pragma unroll
  for (int m = 0; m < 4; m++)
    #pragma unroll
    for (int n = 0; n < 4; n++) {
      #pragma unroll
      for (int r = 0; r < 4; r++) {
        int gm = bm + wm + m * 16 + kq * 4 + r;
        int gn = bn + wn + n * 16 + l15;
        float v = acc[m][n][r];
        if (MODE == 0) {
          ((float*)Cout)[(long)gm * N + gn] = v;
        } else if (MODE == 1) {
          v += bias1[gn] + bias2[gn];
          ((float*)Cout)[(long)gm * N + gn] = v;
        } else {
          if (gn < 1001) {
            long oi = ((long)(gm & 15) * 512 + (gm >> 4)) * 1001 + gn;
            ((float*)Cout)[oi] = v;
          }
        }
      }
    }
}

// ---------- SRU scan (one time-chunk of Lc steps) ----------
// 16384 threads, one per (b,hc). U fp32 chunk (Lc*16 rows, k*1024).
// Software-pipelined: LOAD(next 16) issued before COMPUTE(current 16) so HBM/L2
// latency hides under the sigmoid chain. Requires Lc % 32 == 0 (Lc=256 here).
// Hout nullable (layer 6 fp32 h is never consumed).
__global__ __launch_bounds__(64) void k_scan(const float* __restrict__ U,
                                             const unsigned short* __restrict__ Res16,
                                             const float* __restrict__ vc,
                                             const float* __restrict__ bias,
                                             float* __restrict__ Hout,
                                             unsigned short* __restrict__ H16,
                                             float* __restrict__ cbuf,
                                             int Lc, int k4, int first) {
  int tid = blockIdx.x * 64 + threadIdx.x;
  int b = tid >> 10, hc = tid & 1023;
  float vf = vc[hc], vr = vc[1024 + hc];
  float bfv = bias[hc], brv = bias[1024 + hc];
  const long strideT = 16L * (k4 ? 4 : 3) * 1024;
  const long base0 = (long)b * (k4 ? 4 : 3) * 1024 + hc;
  const long rbase = (long)b * 1024 + hc;
  const long rstride = 16 * 1024;
  float c = first ? 0.f : cbuf[tid];
  float u0a[16], u1a[16], u2a[16], rra[16];
  float u0b[16], u1b[16], u2b[16], rrb[16];

#define LOADX(A0, A1, A2, RR, T0)                                              \
  _Pragma("unroll") for (int j = 0; j < 16; j++) {                             \
    long o = base0 + (long)((T0) + j) * strideT;                               \
    A0[j] = U[o];                                                              \
    A1[j] = U[o + 1024];                                                       \
    A2[j] = U[o + 2048];                                                       \
    RR[j] = k4 ? U[o + 3072] : bf2f(Res16[rbase + (long)((T0) + j) * rstride]);\
  }
#define COMPX(A0, A1, A2, RR, T0)                                              \
  _Pragma("unroll") for (int j = 0; j < 16; j++) {                             \
    float f = sigmoidf_(A1[j] + vf * c + bfv);                                 \
    float r = sigmoidf_(A2[j] + vr * c + brv);                                 \
    c = f * c + (1.f - f) * A0[j];                                             \
    float h = r * c + (1.f - r) * RR[j];                                       \
    long oo = rbase + (long)((T0) + j) * rstride;                              \
    if (Hout) Hout[oo] = h;                                                    \
    if (H16) H16[oo] = f2bf(h);                                                \
  }

  LOADX(u0a, u1a, u2a, rra, 0)
  for (int t0 = 0; t0 < Lc; t0 += 32) {
    if (t0 + 16 < Lc) LOADX(u0b, u1b, u2b, rrb, t0 + 16)
    COMPX(u0a, u1a, u2a, rra, t0)
    if (t0 + 32 < Lc) LOADX(u0a, u1a, u2a, rra, t0 + 32)
    COMPX(u0b, u1b, u2b, rrb, t0 + 16)
  }
#undef LOADX
#undef COMPX
  cbuf[tid] = c;
}

// ---------- LSTM single step ----------
// 256 blocks x 64 threads (ONE wave). Block j owns channels c0=j*4, all 4 gates,
// all 16 batches: the wave's 16 N-columns are (gate = l15>>2, ch = c0 + (l15&3)),
// full K=1024 as 32 chained MFMA. No LDS, no barriers: the 4 gate preacts for a
// given (batch, channel) live in lanes (lane&48)|chl + {0,4,8,12} -> 4 __shfl.
// Prep / HsOutp are pre-offset to this timestep.
__global__ __launch_bounds__(64) void k_lstm_step(
    const unsigned short* __restrict__ Whhb, // (4096,1024) bf16
    const float* __restrict__ Prep,          // (16,4096) fp32 for this t
    const unsigned short* __restrict__ hin,  // (16,1024) bf16
    unsigned short* __restrict__ hout,       // (16,1024) bf16
    float* __restrict__ cst,                 // (16,1024) fp32
    float* __restrict__ HsOutp) {            // (16,1024) fp32 for this t
  const int lane = threadIdx.x;
  const int j = blockIdx.x;
  const int c0 = j * 4;
  const int l15 = lane & 15, kq = lane >> 4;
  const int gate = l15 >> 2, chl = l15 & 3;
  const int wrow = gate * 1024 + c0 + chl;   // Whh row = this lane's N-column
  // issue independent loads early (Prep from L2/LLC, cst from L2)
  float pre[4], cold[4];
  #pragma unroll
  for (int r = 0; r < 4; r++) {
    pre[r] = Prep[(long)(kq * 4 + r) * 4096 + wrow];
    cold[r] = cst[(long)(kq * 4 + r) * 1024 + c0 + chl];
  }
  f32x4 acc = {0.f, 0.f, 0.f, 0.f};
  const unsigned short* hp = hin + l15 * 1024 + kq * 8;
  const unsigned short* wp = Whhb + (long)wrow * 1024 + kq * 8;
  #pragma unroll
  for (int kb = 0; kb < 1024; kb += 32) {
    bf16x8 a = *(const bf16x8*)(hp + kb);
    bf16x8 w = *(const bf16x8*)(wp + kb);
    acc = __builtin_amdgcn_mfma_f32_16x16x32_bf16(a, w, acc, 0, 0, 0);
  }
  #pragma unroll
  for (int r = 0; r < 4; r++) {
    float v = acc[r] + pre[r];
    int base = (lane & 48) | chl;
    float ig = __shfl(v, base);
    float fg = __shfl(v, base + 4);
    float gg = __shfl(v, base + 8);
    float og = __shfl(v, base + 12);
    if (gate == 0) {
      int m = kq * 4 + r;
      float cn = sigmoidf_(fg) * cold[r] + sigmoidf_(ig) * tanhf_(gg);
      float hn = sigmoidf_(og) * tanhf_(cn);
      long ci = (long)m * 1024 + c0 + chl;
      cst[ci] = cn;
      hout[ci] = f2bf(hn);
      HsOutp[ci] = hn;
    }
  }
}

// ---------- host ----------

extern "C" void kernel_launch(void* const* d_in, const int* in_sizes, int n_in,
                              void* d_out, int out_size, void* d_ws, size_t ws_size,
                              hipStream_t stream) {
  const float* x    = (const float*)d_in[0];
  const float* w0   = (const float*)d_in[1];
  const float* vc0  = (const float*)d_in[2];
  const float* b0   = (const float*)d_in[3];
  const float* g0   = (const float*)d_in[4];
  const float* be0  = (const float*)d_in[5];
  const float* Ws   = (const float*)d_in[6];
  const float* VCs  = (const float*)d_in[7];
  const float* Bsi  = (const float*)d_in[8];
  const float* Gs   = (const float*)d_in[9];
  const float* Bes  = (const float*)d_in[10];
  const float* Wih  = (const float*)d_in[11];
  const float* Whh  = (const float*)d_in[12];
  const float* bih  = (const float*)d_in[13];
  const float* bhh  = (const float*)d_in[14];
  const float* gh   = (const float*)d_in[15];
  const float* bh   = (const float*)d_in[16];
  const float* Wout = (const float*)d_in[17];

  char* ws = (char*)d_ws;
  size_t off = 0;
  auto alloc = [&](size_t bytes) {
    size_t r = off;
    off += (bytes + 255) & ~(size_t)255;
    return r;
  };
  unsigned short* W0t   = (unsigned short*)(ws + alloc(4096UL * 128 * 2));      //  1 MB
  unsigned short* Wst   = (unsigned short*)(ws + alloc(6UL * 3072 * 1024 * 2)); // 36 MB
  unsigned short* Wihb  = (unsigned short*)(ws + alloc(4096UL * 1024 * 2));     //  8 MB
  unsigned short* Whhb  = (unsigned short*)(ws + alloc(4096UL * 1024 * 2));     //  8 MB
  unsigned short* Woutt = (unsigned short*)(ws + alloc(1024UL * 1024 * 2));     //  2 MB
  unsigned short* Xn    = (unsigned short*)(ws + alloc(16384UL * 1024 * 2));    // 32 MB
  float*          Hbuf  = (float*)(ws + alloc(16384UL * 1024 * 4));             // 64 MB
  float*          Ubuf  = (float*)(ws + alloc(4096UL * 4096 * 4));              // 64 MB
  unsigned short* hb0   = (unsigned short*)(ws + alloc(16UL * 1024 * 2));
  unsigned short* hb1   = (unsigned short*)(ws + alloc(16UL * 1024 * 2));
  float*          cst   = (float*)(ws + alloc(16UL * 1024 * 4));
  float*          cscan = (float*)(ws + alloc(16UL * 1024 * 4));
  // aliases (lifetimes do not overlap):
  float*          HsOut = Hbuf;              // (512,16,1024) fp32 during LSTM
  unsigned short* H16l6 = Xn + 8192L * 1024; // layer-6 h bf16 (8192 rows)
  unsigned short* LNout = Xn;                // final LN bf16 out (8192 rows)

  // ---- weight conversion ----
  k_cast_t<<<dim3(4096 / 32, 128 / 32), dim3(32, 8), 0, stream>>>(w0, W0t, 128, 4096);
  for (int i = 0; i < 6; i++)
    k_cast_t<<<dim3(3072 / 32, 1024 / 32), dim3(32, 8), 0, stream>>>(
        Ws + (long)i * 1024 * 3072, Wst + (long)i * 3072 * 1024, 1024, 3072);
  k_cast_t<<<dim3(1024 / 32, 1024 / 32), dim3(32, 8), 0, stream>>>(Wout, Woutt, 1024, 1001);
  k_castf<<<4096, 256, 0, stream>>>(Wih, Wihb, 4096 * 1024 / 4);
  k_castf<<<4096, 256, 0, stream>>>(Whh, Whhb, 4096 * 1024 / 4);
  hipMemsetAsync(hb0, 0, 32768 + 32768 + 65536, stream); // hb0, hb1, cst contiguous

  const int CH_T = 256;           // timesteps per chunk
  const int CH_R = CH_T * 16;     // rows per chunk (4096)

  // ---- SRU layer 0 (k=4, K=128) ----
  k_ln0<<<16384, 128, 0, stream>>>(x, Xn, g0, be0);
  for (int c = 0; c < 4; c++) {
    k_gemm<0><<<dim3(4096 / 128, CH_R / 128), 256, 0, stream>>>(
        Xn + (long)c * CH_R * 128, W0t, Ubuf, nullptr, nullptr, CH_R, 4096, 128);
    k_scan<<<256, 64, 0, stream>>>(Ubuf, nullptr, vc0, b0,
                                   Hbuf + (long)c * CH_R * 1024, nullptr, cscan,
                                   CH_T, 1, c == 0);
  }

  // ---- SRU layers 1..6 (k=3, K=1024) ----
  for (int i = 0; i < 6; i++) {
    int L = (i < 3) ? 1024 : 512;
    int rows = L * 16;
    int avg = (i == 3) ? 1 : 0;
    k_ln<<<rows, 256, 0, stream>>>(Hbuf, Xn, Gs + i * 1024, Bes + i * 1024, avg);
    int nch = rows / CH_R;
    for (int c = 0; c < nch; c++) {
      k_gemm<0><<<dim3(3072 / 128, CH_R / 128), 256, 0, stream>>>(
          Xn + (long)c * CH_R * 1024, Wst + (long)i * 3072 * 1024, Ubuf, nullptr, nullptr,
          CH_R, 3072, 1024);
      k_scan<<<256, 64, 0, stream>>>(Ubuf, Xn + (long)c * CH_R * 1024,
                                     VCs + i * 2048, Bsi + i * 2048,
                                     (i == 5) ? nullptr : (Hbuf + (long)c * CH_R * 1024),
                                     (i == 5) ? (H16l6 + (long)c * CH_R * 1024) : nullptr,
                                     cscan, CH_T, 0, c == 0);
    }
  }

  // ---- LSTM: chunked input projection + 512 step kernels ----
  // (HsOut aliases Hbuf: layer-6 fp32 h is no longer needed)
  const int LCH_T = 256, LCH_R = LCH_T * 16; // 4096 rows per chunk (fills Ubuf exactly)
  for (int c = 0; c < 2; c++) {
    k_gemm<1><<<dim3(4096 / 128, LCH_R / 128), 256, 0, stream>>>(
        H16l6 + (long)c * LCH_R * 1024, Wihb, Ubuf, bih, bhh, LCH_R, 4096, 1024);
    for (int tl = 0; tl < LCH_T; tl++) {
      int tg = c * LCH_T + tl;
      unsigned short* hin = (tg & 1) ? hb1 : hb0;
      unsigned short* hout = (tg & 1) ? hb0 : hb1;
      k_lstm_step<<<256, 64, 0, stream>>>(Whhb, Ubuf + (long)tl * 16 * 4096, hin, hout,
                                          cst, HsOut + (long)tg * 16 * 1024);
    }
  }

  // ---- final LN + output projection ----
  k_ln<<<8192, 256, 0, stream>>>(HsOut, LNout, gh, bh, 0);
  k_gemm<2><<<dim3(1024 / 128, 8192 / 128), 256, 0, stream>>>(LNout, Woutt, d_out, nullptr,
                                                              nullptr, 8192, 1024, 1024);
}

// Round 6
// 6158.238 us; speedup vs baseline: 1.1728x; 1.1728x over previous
//
#include <hip/hip_runtime.h>

typedef __bf16 bf16x8 __attribute__((ext_vector_type(8)));
typedef float f32x4 __attribute__((ext_vector_type(4)));

__device__ __forceinline__ unsigned short f2bf(float f) {
  unsigned u = __builtin_bit_cast(unsigned, f);
  u += 0x7fffu + ((u >> 16) & 1u);
  return (unsigned short)(u >> 16);
}
__device__ __forceinline__ float bf2f(unsigned short h) {
  unsigned u = ((unsigned)h) << 16;
  return __builtin_bit_cast(float, u);
}
__device__ __forceinline__ float sigmoidf_(float x) {
  return 1.f / (1.f + __expf(-x));
}
__device__ __forceinline__ float tanhf_(float x) {
  return 1.f - 2.f / (__expf(2.f * x) + 1.f);
}
// async global->LDS, 16B per lane. LDS dest must be wave-uniform base + lane*16.
__device__ __forceinline__ void gload16(const unsigned short* g, unsigned short* l) {
  __builtin_amdgcn_global_load_lds((const __attribute__((address_space(1))) void*)g,
                                   (__attribute__((address_space(3))) void*)l, 16, 0, 0);
}

// ---------- weight cast kernels ----------

__global__ __launch_bounds__(256) void k_castf(const float* __restrict__ src,
                                               unsigned short* __restrict__ dst, int n4) {
  int i = blockIdx.x * 256 + threadIdx.x;
  if (i < n4) {
    float4 v = ((const float4*)src)[i];
    ushort4 o;
    o.x = f2bf(v.x); o.y = f2bf(v.y); o.z = f2bf(v.z); o.w = f2bf(v.w);
    ((ushort4*)dst)[i] = o;
  }
}

// transpose-cast: src fp32 (K,N) row-major -> dst bf16 (Npad,K) row-major, zero-pad n>=N
__global__ void k_cast_t(const float* __restrict__ src, unsigned short* __restrict__ dst,
                         int K, int N) {
  __shared__ float tile[32][33];
  int nx = blockIdx.x * 32, ky = blockIdx.y * 32;
  int tx = threadIdx.x, ty = threadIdx.y; // 32 x 8
  #pragma unroll
  for (int j = 0; j < 32; j += 8) {
    int n = nx + tx, k = ky + ty + j;
    tile[ty + j][tx] = (n < N) ? src[(long)k * N + n] : 0.f;
  }
  __syncthreads();
  #pragma unroll
  for (int j = 0; j < 32; j += 8) {
    int n = nx + ty + j, k = ky + tx;
    dst[(long)n * K + k] = f2bf(tile[tx][ty + j]);
  }
}

// ---------- LayerNorm kernels ----------

// layer-0 LN with (B,T,F)->(T,B,F) transpose, F=128, fp32 in -> bf16 out
__global__ __launch_bounds__(128) void k_ln0(const float* __restrict__ x,
                                             unsigned short* __restrict__ out,
                                             const float* __restrict__ g,
                                             const float* __restrict__ be) {
  int row = blockIdx.x;            // t*16 + b
  int t = row >> 4, b = row & 15;
  const float* src = x + ((long)b * 1024 + t) * 128;
  int i = threadIdx.x;
  float v = src[i];
  float s = v, q = v * v;
  #pragma unroll
  for (int off = 32; off > 0; off >>= 1) {
    s += __shfl_down(s, off);
    q += __shfl_down(q, off);
  }
  __shared__ float red[4];
  int wv = i >> 6;
  if ((i & 63) == 0) { red[wv] = s; red[2 + wv] = q; }
  __syncthreads();
  float S = red[0] + red[1], Q = red[2] + red[3];
  float mean = S * (1.f / 128.f);
  float var = Q * (1.f / 128.f) - mean * mean;
  float rs = rsqrtf(var + 1e-5f);
  out[(long)row * 128 + i] = f2bf((v - mean) * rs * g[i] + be[i]);
}

// generic LN over C=1024 fp32 rows -> bf16 out16; avg=1 averages time-pairs
__global__ __launch_bounds__(256) void k_ln(const float* __restrict__ in,
                                            unsigned short* __restrict__ out16,
                                            const float* __restrict__ g,
                                            const float* __restrict__ be, int avg) {
  int row = blockIdx.x;
  int tid = threadIdx.x;
  int col = tid * 4;
  float xv[4];
  if (avg) {
    int l = row >> 4, b = row & 15;
    const float* r0 = in + ((long)(2 * l) * 16 + b) * 1024;
    const float* r1 = r0 + 16 * 1024;
    float4 a = *(const float4*)(r0 + col);
    float4 bb = *(const float4*)(r1 + col);
    xv[0] = 0.5f * (a.x + bb.x);
    xv[1] = 0.5f * (a.y + bb.y);
    xv[2] = 0.5f * (a.z + bb.z);
    xv[3] = 0.5f * (a.w + bb.w);
  } else {
    float4 a = *(const float4*)(in + (long)row * 1024 + col);
    xv[0] = a.x; xv[1] = a.y; xv[2] = a.z; xv[3] = a.w;
  }
  float s = xv[0] + xv[1] + xv[2] + xv[3];
  float q = xv[0]*xv[0] + xv[1]*xv[1] + xv[2]*xv[2] + xv[3]*xv[3];
  #pragma unroll
  for (int off = 32; off > 0; off >>= 1) {
    s += __shfl_down(s, off);
    q += __shfl_down(q, off);
  }
  __shared__ float red[8];
  int wv = tid >> 6;
  if ((tid & 63) == 0) { red[wv] = s; red[4 + wv] = q; }
  __syncthreads();
  float S = red[0] + red[1] + red[2] + red[3];
  float Q = red[4] + red[5] + red[6] + red[7];
  float mean = S * (1.f / 1024.f);
  float var = Q * (1.f / 1024.f) - mean * mean;
  float rs = rsqrtf(var + 1e-5f);
  ushort4 o;
  o.x = f2bf((xv[0] - mean) * rs * g[col + 0] + be[col + 0]);
  o.y = f2bf((xv[1] - mean) * rs * g[col + 1] + be[col + 1]);
  o.z = f2bf((xv[2] - mean) * rs * g[col + 2] + be[col + 2]);
  o.w = f2bf((xv[3] - mean) * rs * g[col + 3] + be[col + 3]);
  *(ushort4*)(out16 + (long)row * 1024 + col) = o;
}

// ---------- GEMM: A (M,K) bf16 x Bt (N,K) bf16 ----------
// 128x128 tile, BK=64, 4 waves (2x2), each wave 64x64 = 4x4 fragments of 16x16x32.
// Staging via global_load_lds width=16 (m97 structure).
// XCD-aware block swizzle (T1): all launch grids have nwg%8==0 -> bijective.
// MODE 0: fp32 out (M,N). MODE 1: + bias1[n]+bias2[n], fp32 out.
// MODE 2: fp32 scatter to (B=16, L=512, 1001) with n<1001 mask.
// Requires M%128==0, N%128==0, K%64==0.
template <int MODE>
__global__ __launch_bounds__(256) void k_gemm(const unsigned short* __restrict__ A,
                                              const unsigned short* __restrict__ Bt,
                                              void* __restrict__ Cout,
                                              const float* __restrict__ bias1,
                                              const float* __restrict__ bias2,
                                              int M, int N, int K) {
  __shared__ unsigned short As[128][64]; // linear (unpadded) -- required by global_load_lds
  __shared__ unsigned short Bs[128][64];
  // XCD swizzle: hw block id b lands on XCD b%8; give each XCD a contiguous tile range.
  const int nwg = gridDim.x * gridDim.y;
  const int bid = blockIdx.y * gridDim.x + blockIdx.x;
  const int swz = (bid & 7) * (nwg >> 3) + (bid >> 3);
  const int bn = (swz % gridDim.x) * 128, bm = (swz / gridDim.x) * 128;
  const int tid = threadIdx.x;
  const int wave = tid >> 6, lane = tid & 63;
  const int wm = (wave >> 1) * 64, wn = (wave & 1) * 64;
  const int l15 = lane & 15, kq = lane >> 4;
  f32x4 acc[4][4] = {};
  const int r0 = tid >> 3;
  const int c0 = (tid & 7) * 8;
  const unsigned short* Ap = A + (long)(bm + r0) * K + c0;
  const unsigned short* Bp = Bt + (long)(bn + r0) * K + c0;
  for (int kb = 0; kb < K; kb += 64) {
    #pragma unroll
    for (int i = 0; i < 4; i++) {
      gload16(Ap + (long)(i * 32) * K + kb, &As[i * 32 + r0][c0]);
      gload16(Bp + (long)(i * 32) * K + kb, &Bs[i * 32 + r0][c0]);
    }
    __syncthreads();
    #pragma unroll
    for (int kk = 0; kk < 2; kk++) {
      const int kcol = kk * 32 + kq * 8;
      bf16x8 a[4], b[4];
      #pragma unroll
      for (int m = 0; m < 4; m++) a[m] = *(const bf16x8*)&As[wm + m * 16 + l15][kcol];
      #pragma unroll
      for (int n = 0; n < 4; n++) b[n] = *(const bf16x8*)&Bs[wn + n * 16 + l15][kcol];
      #pragma unroll
      for (int m = 0; m < 4; m++)
        #pragma unroll
        for (int n = 0; n < 4; n++)
          acc[m][n] = __builtin_amdgcn_mfma_f32_16x16x32_bf16(a[m], b[n], acc[m][n], 0, 0, 0);
    }
    __syncthreads();
  }
  #pragma unroll
  for (int m = 0; m < 4; m++)
    #pragma unroll
    for (int n = 0; n < 4; n++) {
      #pragma unroll
      for (int r = 0; r < 4; r++) {
        int gm = bm + wm + m * 16 + kq * 4 + r;
        int gn = bn + wn + n * 16 + l15;
        float v = acc[m][n][r];
        if (MODE == 0) {
          ((float*)Cout)[(long)gm * N + gn] = v;
        } else if (MODE == 1) {
          v += bias1[gn] + bias2[gn];
          ((float*)Cout)[(long)gm * N + gn] = v;
        } else {
          if (gn < 1001) {
            long oi = ((long)(gm & 15) * 512 + (gm >> 4)) * 1001 + gn;
            ((float*)Cout)[oi] = v;
          }
        }
      }
    }
}

// ---------- SRU scan (one time-chunk of Lc steps) ----------
// 16384 threads, one per (b,hc). U fp32 chunk (Lc*16 rows, k*1024).
// Res16 bf16 residual rows (nullptr if k4: residual is U col 3).
// 16-deep time-batch (R4-proven). Hout nullable (layer-6 fp32 h never consumed).
__global__ __launch_bounds__(64) void k_scan(const float* __restrict__ U,
                                             const unsigned short* __restrict__ Res16,
                                             const float* __restrict__ vc,
                                             const float* __restrict__ bias,
                                             float* __restrict__ Hout,
                                             unsigned short* __restrict__ H16,
                                             float* __restrict__ cbuf,
                                             int Lc, int k4, int first) {
  int tid = blockIdx.x * 64 + threadIdx.x;
  int b = tid >> 10, hc = tid & 1023;
  float vf = vc[hc], vr = vc[1024 + hc];
  float bfv = bias[hc], brv = bias[1024 + hc];
  const int k = k4 ? 4 : 3;
  const long strideT = 16L * k * 1024;
  const long base0 = (long)b * k * 1024 + hc;
  const long rbase = (long)b * 1024 + hc;
  const long rstride = 16 * 1024;
  float c = first ? 0.f : cbuf[tid];
  for (int t0 = 0; t0 < Lc; t0 += 16) {
    float u0[16], u1[16], u2[16], rr[16];
    #pragma unroll
    for (int j = 0; j < 16; j++) {
      long o = base0 + (long)(t0 + j) * strideT;
      u0[j] = U[o];
      u1[j] = U[o + 1024];
      u2[j] = U[o + 2048];
      rr[j] = k4 ? U[o + 3072] : bf2f(Res16[rbase + (long)(t0 + j) * rstride]);
    }
    #pragma unroll
    for (int j = 0; j < 16; j++) {
      float f = sigmoidf_(u1[j] + vf * c + bfv);
      float r = sigmoidf_(u2[j] + vr * c + brv);
      c = f * c + (1.f - f) * u0[j];
      float h = r * c + (1.f - r) * rr[j];
      long oo = rbase + (long)(t0 + j) * rstride;
      if (Hout) Hout[oo] = h;
      if (H16) H16[oo] = f2bf(h);
    }
  }
  cbuf[tid] = c;
}

// ---------- LSTM single step ----------
// 256 blocks x 256 threads (4 waves). Block j owns channels c0=j*4, all 4 gates,
// all 16 batches. K=1024 split across 4 waves, LDS reduce, then cell update.
// Prep / cst loads hoisted to kernel top (independent of MFMA; hide under compute).
// Prep / HsOutp are pre-offset to this timestep.
__global__ __launch_bounds__(256) void k_lstm_step(
    const unsigned short* __restrict__ Whhb, // (4096,1024) bf16
    const float* __restrict__ Prep,          // (16,4096) fp32 for this t
    const unsigned short* __restrict__ hin,  // (16,1024) bf16
    unsigned short* __restrict__ hout,       // (16,1024) bf16
    float* __restrict__ cst,                 // (16,1024) fp32
    float* __restrict__ HsOutp) {            // (16,1024) fp32 for this t
  const int tid = threadIdx.x;
  const int wave = tid >> 6, lane = tid & 63;
  const int j = blockIdx.x;
  const int c0 = j * 4;
  const int l15 = lane & 15, kq = lane >> 4;
  const int wrow = (l15 >> 2) * 1024 + c0 + (l15 & 3);
  // hoisted independent loads (used after the barriers)
  const int pm = tid >> 4, pcol = tid & 15;               // G-phase mapping
  float pre = Prep[(long)pm * 4096 + (pcol >> 2) * 1024 + c0 + (pcol & 3)];
  float cold = 0.f;
  long ci = 0;
  if (tid < 64) {
    int m = tid & 15, chl = tid >> 4;
    ci = (long)m * 1024 + c0 + chl;
    cold = cst[ci];
  }
  f32x4 acc = {0.f, 0.f, 0.f, 0.f};
  const unsigned short* hp = hin + l15 * 1024 + wave * 256 + kq * 8;
  const unsigned short* wp = Whhb + (long)wrow * 1024 + wave * 256 + kq * 8;
  #pragma unroll
  for (int kb = 0; kb < 256; kb += 32) {
    bf16x8 a = *(const bf16x8*)(hp + kb);
    bf16x8 w = *(const bf16x8*)(wp + kb);
    acc = __builtin_amdgcn_mfma_f32_16x16x32_bf16(a, w, acc, 0, 0, 0);
  }
  __shared__ float P[4][16][16];
  __shared__ float G[16][16];
  #pragma unroll
  for (int r = 0; r < 4; r++) {
    int m = kq * 4 + r; // batch
    P[wave][m][l15] = acc[r];
  }
  __syncthreads();
  G[pm][pcol] = P[0][pm][pcol] + P[1][pm][pcol] + P[2][pm][pcol] + P[3][pm][pcol] + pre;
  __syncthreads();
  if (tid < 64) {
    int m = tid & 15, chl = tid >> 4;
    float ig = G[m][0 * 4 + chl];
    float fg = G[m][1 * 4 + chl];
    float gg = G[m][2 * 4 + chl];
    float og = G[m][3 * 4 + chl];
    float cn = sigmoidf_(fg) * cold + sigmoidf_(ig) * tanhf_(gg);
    float hn = sigmoidf_(og) * tanhf_(cn);
    cst[ci] = cn;
    hout[ci] = f2bf(hn);
    HsOutp[ci] = hn;
  }
}

// ---------- host ----------

extern "C" void kernel_launch(void* const* d_in, const int* in_sizes, int n_in,
                              void* d_out, int out_size, void* d_ws, size_t ws_size,
                              hipStream_t stream) {
  const float* x    = (const float*)d_in[0];
  const float* w0   = (const float*)d_in[1];
  const float* vc0  = (const float*)d_in[2];
  const float* b0   = (const float*)d_in[3];
  const float* g0   = (const float*)d_in[4];
  const float* be0  = (const float*)d_in[5];
  const float* Ws   = (const float*)d_in[6];
  const float* VCs  = (const float*)d_in[7];
  const float* Bsi  = (const float*)d_in[8];
  const float* Gs   = (const float*)d_in[9];
  const float* Bes  = (const float*)d_in[10];
  const float* Wih  = (const float*)d_in[11];
  const float* Whh  = (const float*)d_in[12];
  const float* bih  = (const float*)d_in[13];
  const float* bhh  = (const float*)d_in[14];
  const float* gh   = (const float*)d_in[15];
  const float* bh   = (const float*)d_in[16];
  const float* Wout = (const float*)d_in[17];

  char* ws = (char*)d_ws;
  size_t off = 0;
  auto alloc = [&](size_t bytes) {
    size_t r = off;
    off += (bytes + 255) & ~(size_t)255;
    return r;
  };
  unsigned short* W0t   = (unsigned short*)(ws + alloc(4096UL * 128 * 2));      //  1 MB
  unsigned short* Wst   = (unsigned short*)(ws + alloc(6UL * 3072 * 1024 * 2)); // 36 MB
  unsigned short* Wihb  = (unsigned short*)(ws + alloc(4096UL * 1024 * 2));     //  8 MB
  unsigned short* Whhb  = (unsigned short*)(ws + alloc(4096UL * 1024 * 2));     //  8 MB
  unsigned short* Woutt = (unsigned short*)(ws + alloc(1024UL * 1024 * 2));     //  2 MB
  unsigned short* Xn    = (unsigned short*)(ws + alloc(16384UL * 1024 * 2));    // 32 MB
  float*          Hbuf  = (float*)(ws + alloc(16384UL * 1024 * 4));             // 64 MB
  float*          Ubuf  = (float*)(ws + alloc(4096UL * 4096 * 4));              // 64 MB
  unsigned short* hb0   = (unsigned short*)(ws + alloc(16UL * 1024 * 2));
  unsigned short* hb1   = (unsigned short*)(ws + alloc(16UL * 1024 * 2));
  float*          cst   = (float*)(ws + alloc(16UL * 1024 * 4));
  float*          cscan = (float*)(ws + alloc(16UL * 1024 * 4));
  // aliases (lifetimes do not overlap):
  float*          HsOut = Hbuf;              // (512,16,1024) fp32 during LSTM
  unsigned short* H16l6 = Xn + 8192L * 1024; // layer-6 h bf16 (8192 rows)
  unsigned short* LNout = Xn;                // final LN bf16 out (8192 rows)

  // ---- weight conversion ----
  k_cast_t<<<dim3(4096 / 32, 128 / 32), dim3(32, 8), 0, stream>>>(w0, W0t, 128, 4096);
  for (int i = 0; i < 6; i++)
    k_cast_t<<<dim3(3072 / 32, 1024 / 32), dim3(32, 8), 0, stream>>>(
        Ws + (long)i * 1024 * 3072, Wst + (long)i * 3072 * 1024, 1024, 3072);
  k_cast_t<<<dim3(1024 / 32, 1024 / 32), dim3(32, 8), 0, stream>>>(Wout, Woutt, 1024, 1001);
  k_castf<<<4096, 256, 0, stream>>>(Wih, Wihb, 4096 * 1024 / 4);
  k_castf<<<4096, 256, 0, stream>>>(Whh, Whhb, 4096 * 1024 / 4);
  hipMemsetAsync(hb0, 0, 32768 + 32768 + 65536, stream); // hb0, hb1, cst contiguous

  const int CH_T = 256;           // timesteps per chunk
  const int CH_R = CH_T * 16;     // rows per chunk (4096)

  // ---- SRU layer 0 (k=4, K=128) ----
  k_ln0<<<16384, 128, 0, stream>>>(x, Xn, g0, be0);
  for (int c = 0; c < 4; c++) {
    k_gemm<0><<<dim3(4096 / 128, CH_R / 128), 256, 0, stream>>>(
        Xn + (long)c * CH_R * 128, W0t, Ubuf, nullptr, nullptr, CH_R, 4096, 128);
    k_scan<<<256, 64, 0, stream>>>(Ubuf, nullptr, vc0, b0,
                                   Hbuf + (long)c * CH_R * 1024, nullptr, cscan,
                                   CH_T, 1, c == 0);
  }

  // ---- SRU layers 1..6 (k=3, K=1024) ----
  for (int i = 0; i < 6; i++) {
    int L = (i < 3) ? 1024 : 512;
    int rows = L * 16;
    int avg = (i == 3) ? 1 : 0;
    k_ln<<<rows, 256, 0, stream>>>(Hbuf, Xn, Gs + i * 1024, Bes + i * 1024, avg);
    int nch = rows / CH_R;
    for (int c = 0; c < nch; c++) {
      k_gemm<0><<<dim3(3072 / 128, CH_R / 128), 256, 0, stream>>>(
          Xn + (long)c * CH_R * 1024, Wst + (long)i * 3072 * 1024, Ubuf, nullptr, nullptr,
          CH_R, 3072, 1024);
      k_scan<<<256, 64, 0, stream>>>(Ubuf, Xn + (long)c * CH_R * 1024,
                                     VCs + i * 2048, Bsi + i * 2048,
                                     (i == 5) ? nullptr : (Hbuf + (long)c * CH_R * 1024),
                                     (i == 5) ? (H16l6 + (long)c * CH_R * 1024) : nullptr,
                                     cscan, CH_T, 0, c == 0);
    }
  }

  // ---- LSTM: chunked input projection + 512 step kernels ----
  // (HsOut aliases Hbuf: layer-6 fp32 h is no longer needed)
  const int LCH_T = 256, LCH_R = LCH_T * 16; // 4096 rows per chunk (fills Ubuf exactly)
  for (int c = 0; c < 2; c++) {
    k_gemm<1><<<dim3(4096 / 128, LCH_R / 128), 256, 0, stream>>>(
        H16l6 + (long)c * LCH_R * 1024, Wihb, Ubuf, bih, bhh, LCH_R, 4096, 1024);
    for (int tl = 0; tl < LCH_T; tl++) {
      int tg = c * LCH_T + tl;
      unsigned short* hin = (tg & 1) ? hb1 : hb0;
      unsigned short* hout = (tg & 1) ? hb0 : hb1;
      k_lstm_step<<<256, 256, 0, stream>>>(Whhb, Ubuf + (long)tl * 16 * 4096, hin, hout,
                                           cst, HsOut + (long)tg * 16 * 1024);
    }
  }

  // ---- final LN + output projection ----
  k_ln<<<8192, 256, 0, stream>>>(HsOut, LNout, gh, bh, 0);
  k_gemm<2><<<dim3(1024 / 128, 8192 / 128), 256, 0, stream>>>(LNout, Woutt, d_out, nullptr,
                                                              nullptr, 8192, 1024, 1024);
}

// Round 7
// 5675.828 us; speedup vs baseline: 1.2725x; 1.0850x over previous
//
#include <hip/hip_runtime.h>

typedef __bf16 bf16x8 __attribute__((ext_vector_type(8)));
typedef float f32x4 __attribute__((ext_vector_type(4)));

__device__ __forceinline__ unsigned short f2bf(float f) {
  unsigned u = __builtin_bit_cast(unsigned, f);
  u += 0x7fffu + ((u >> 16) & 1u);
  return (unsigned short)(u >> 16);
}
__device__ __forceinline__ float bf2f(unsigned short h) {
  unsigned u = ((unsigned)h) << 16;
  return __builtin_bit_cast(float, u);
}
__device__ __forceinline__ float sigmoidf_(float x) {
  return 1.f / (1.f + __expf(-x));
}
__device__ __forceinline__ float tanhf_(float x) {
  return 1.f - 2.f / (__expf(2.f * x) + 1.f);
}
// async global->LDS, 16B per lane. LDS dest must be wave-uniform base + lane*16.
__device__ __forceinline__ void gload16(const unsigned short* g, unsigned short* l) {
  __builtin_amdgcn_global_load_lds((const __attribute__((address_space(1))) void*)g,
                                   (__attribute__((address_space(3))) void*)l, 16, 0, 0);
}

// ---------- weight cast kernels ----------

__global__ __launch_bounds__(256) void k_castf(const float* __restrict__ src,
                                               unsigned short* __restrict__ dst, int n4) {
  int i = blockIdx.x * 256 + threadIdx.x;
  if (i < n4) {
    float4 v = ((const float4*)src)[i];
    ushort4 o;
    o.x = f2bf(v.x); o.y = f2bf(v.y); o.z = f2bf(v.z); o.w = f2bf(v.w);
    ((ushort4*)dst)[i] = o;
  }
}

// transpose-cast: src fp32 (K,N) row-major -> dst bf16 (Npad,K) row-major, zero-pad n>=N
__global__ void k_cast_t(const float* __restrict__ src, unsigned short* __restrict__ dst,
                         int K, int N) {
  __shared__ float tile[32][33];
  int nx = blockIdx.x * 32, ky = blockIdx.y * 32;
  int tx = threadIdx.x, ty = threadIdx.y; // 32 x 8
  #pragma unroll
  for (int j = 0; j < 32; j += 8) {
    int n = nx + tx, k = ky + ty + j;
    tile[ty + j][tx] = (n < N) ? src[(long)k * N + n] : 0.f;
  }
  __syncthreads();
  #pragma unroll
  for (int j = 0; j < 32; j += 8) {
    int n = nx + ty + j, k = ky + tx;
    dst[(long)n * K + k] = f2bf(tile[tx][ty + j]);
  }
}

// ---------- LayerNorm kernels ----------

// layer-0 LN with (B,T,F)->(T,B,F) transpose, F=128, fp32 in -> bf16 out
__global__ __launch_bounds__(128) void k_ln0(const float* __restrict__ x,
                                             unsigned short* __restrict__ out,
                                             const float* __restrict__ g,
                                             const float* __restrict__ be) {
  int row = blockIdx.x;            // t*16 + b
  int t = row >> 4, b = row & 15;
  const float* src = x + ((long)b * 1024 + t) * 128;
  int i = threadIdx.x;
  float v = src[i];
  float s = v, q = v * v;
  #pragma unroll
  for (int off = 32; off > 0; off >>= 1) {
    s += __shfl_down(s, off);
    q += __shfl_down(q, off);
  }
  __shared__ float red[4];
  int wv = i >> 6;
  if ((i & 63) == 0) { red[wv] = s; red[2 + wv] = q; }
  __syncthreads();
  float S = red[0] + red[1], Q = red[2] + red[3];
  float mean = S * (1.f / 128.f);
  float var = Q * (1.f / 128.f) - mean * mean;
  float rs = rsqrtf(var + 1e-5f);
  out[(long)row * 128 + i] = f2bf((v - mean) * rs * g[i] + be[i]);
}

// generic LN over C=1024 fp32 rows -> bf16 out16; avg=1 averages time-pairs
__global__ __launch_bounds__(256) void k_ln(const float* __restrict__ in,
                                            unsigned short* __restrict__ out16,
                                            const float* __restrict__ g,
                                            const float* __restrict__ be, int avg) {
  int row = blockIdx.x;
  int tid = threadIdx.x;
  int col = tid * 4;
  float xv[4];
  if (avg) {
    int l = row >> 4, b = row & 15;
    const float* r0 = in + ((long)(2 * l) * 16 + b) * 1024;
    const float* r1 = r0 + 16 * 1024;
    float4 a = *(const float4*)(r0 + col);
    float4 bb = *(const float4*)(r1 + col);
    xv[0] = 0.5f * (a.x + bb.x);
    xv[1] = 0.5f * (a.y + bb.y);
    xv[2] = 0.5f * (a.z + bb.z);
    xv[3] = 0.5f * (a.w + bb.w);
  } else {
    float4 a = *(const float4*)(in + (long)row * 1024 + col);
    xv[0] = a.x; xv[1] = a.y; xv[2] = a.z; xv[3] = a.w;
  }
  float s = xv[0] + xv[1] + xv[2] + xv[3];
  float q = xv[0]*xv[0] + xv[1]*xv[1] + xv[2]*xv[2] + xv[3]*xv[3];
  #pragma unroll
  for (int off = 32; off > 0; off >>= 1) {
    s += __shfl_down(s, off);
    q += __shfl_down(q, off);
  }
  __shared__ float red[8];
  int wv = tid >> 6;
  if ((tid & 63) == 0) { red[wv] = s; red[4 + wv] = q; }
  __syncthreads();
  float S = red[0] + red[1] + red[2] + red[3];
  float Q = red[4] + red[5] + red[6] + red[7];
  float mean = S * (1.f / 1024.f);
  float var = Q * (1.f / 1024.f) - mean * mean;
  float rs = rsqrtf(var + 1e-5f);
  ushort4 o;
  o.x = f2bf((xv[0] - mean) * rs * g[col + 0] + be[col + 0]);
  o.y = f2bf((xv[1] - mean) * rs * g[col + 1] + be[col + 1]);
  o.z = f2bf((xv[2] - mean) * rs * g[col + 2] + be[col + 2]);
  o.w = f2bf((xv[3] - mean) * rs * g[col + 3] + be[col + 3]);
  *(ushort4*)(out16 + (long)row * 1024 + col) = o;
}

// ---------- GEMM: A (M,K) bf16 x Bt (N,K) bf16 ----------
// 128x128 tile, BK=64, 4 waves (2x2), each wave 64x64 = 4x4 fragments of 16x16x32.
// Staging via global_load_lds width=16 (m97 structure). XCD swizzle (nwg%8==0).
// MODE 0: fp32 out (M,N). MODE 1: + bias1[n]+bias2[n], fp32 out.
// MODE 2: fp32 scatter to (B=16, L=512, 1001) with n<1001 mask.
template <int MODE>
__global__ __launch_bounds__(256) void k_gemm(const unsigned short* __restrict__ A,
                                              const unsigned short* __restrict__ Bt,
                                              void* __restrict__ Cout,
                                              const float* __restrict__ bias1,
                                              const float* __restrict__ bias2,
                                              int M, int N, int K) {
  __shared__ unsigned short As[128][64];
  __shared__ unsigned short Bs[128][64];
  const int nwg = gridDim.x * gridDim.y;
  const int bid = blockIdx.y * gridDim.x + blockIdx.x;
  const int swz = (bid & 7) * (nwg >> 3) + (bid >> 3);
  const int bn = (swz % gridDim.x) * 128, bm = (swz / gridDim.x) * 128;
  const int tid = threadIdx.x;
  const int wave = tid >> 6, lane = tid & 63;
  const int wm = (wave >> 1) * 64, wn = (wave & 1) * 64;
  const int l15 = lane & 15, kq = lane >> 4;
  f32x4 acc[4][4] = {};
  const int r0 = tid >> 3;
  const int c0 = (tid & 7) * 8;
  const unsigned short* Ap = A + (long)(bm + r0) * K + c0;
  const unsigned short* Bp = Bt + (long)(bn + r0) * K + c0;
  for (int kb = 0; kb < K; kb += 64) {
    #pragma unroll
    for (int i = 0; i < 4; i++) {
      gload16(Ap + (long)(i * 32) * K + kb, &As[i * 32 + r0][c0]);
      gload16(Bp + (long)(i * 32) * K + kb, &Bs[i * 32 + r0][c0]);
    }
    __syncthreads();
    #pragma unroll
    for (int kk = 0; kk < 2; kk++) {
      const int kcol = kk * 32 + kq * 8;
      bf16x8 a[4], b[4];
      #pragma unroll
      for (int m = 0; m < 4; m++) a[m] = *(const bf16x8*)&As[wm + m * 16 + l15][kcol];
      #pragma unroll
      for (int n = 0; n < 4; n++) b[n] = *(const bf16x8*)&Bs[wn + n * 16 + l15][kcol];
      #pragma unroll
      for (int m = 0; m < 4; m++)
        #pragma unroll
        for (int n = 0; n < 4; n++)
          acc[m][n] = __builtin_amdgcn_mfma_f32_16x16x32_bf16(a[m], b[n], acc[m][n], 0, 0, 0);
    }
    __syncthreads();
  }
  #pragma unroll
  for (int m = 0; m < 4; m++)
    #pragma unroll
    for (int n = 0; n < 4; n++) {
      #pragma unroll
      for (int r = 0; r < 4; r++) {
        int gm = bm + wm + m * 16 + kq * 4 + r;
        int gn = bn + wn + n * 16 + l15;
        float v = acc[m][n][r];
        if (MODE == 0) {
          ((float*)Cout)[(long)gm * N + gn] = v;
        } else if (MODE == 1) {
          v += bias1[gn] + bias2[gn];
          ((float*)Cout)[(long)gm * N + gn] = v;
        } else {
          if (gn < 1001) {
            long oi = ((long)(gm & 15) * 512 + (gm >> 4)) * 1001 + gn;
            ((float*)Cout)[oi] = v;
          }
        }
      }
    }
}

// ---------- fused GEMM(chunk c) || SRU-scan(chunk c-1) ----------
// Heterogeneous block roles, NO cross-part synchronization (disjoint buffers;
// Ubuf double-buffered by the host). Blocks [0,64): scan (256 thr = 4 waves,
// sid = bid*256+tid matches k_scan's linear (b,hc) id space). Blocks [64,...):
// MODE-0 GEMM identical to k_gemm (bid-64 flat id, XCD swizzle, nwg%8==0).
__global__ __launch_bounds__(256) void k_gemm_scan(
    const unsigned short* __restrict__ A, const unsigned short* __restrict__ Bt,
    float* __restrict__ Cout, int M, int N, int K,
    const float* __restrict__ sU, const unsigned short* __restrict__ sRes16,
    const float* __restrict__ vc, const float* __restrict__ bias,
    float* __restrict__ sHout, unsigned short* __restrict__ sH16,
    float* __restrict__ cbuf, int Lc, int k4, int sfirst) {
  __shared__ unsigned short As[128][64];
  __shared__ unsigned short Bs[128][64];
  const int bid = blockIdx.x;
  const int tid = threadIdx.x;
  if (bid < 64) {
    // ---------------- scan part (R6-proven body, 4-wave blocks) ----------------
    int sid = bid * 256 + tid;
    int b = sid >> 10, hc = sid & 1023;
    float vf = vc[hc], vr = vc[1024 + hc];
    float bfv = bias[hc], brv = bias[1024 + hc];
    const int k = k4 ? 4 : 3;
    const long strideT = 16L * k * 1024;
    const long base0 = (long)b * k * 1024 + hc;
    const long rbase = (long)b * 1024 + hc;
    const long rstride = 16 * 1024;
    float c = sfirst ? 0.f : cbuf[sid];
    for (int t0 = 0; t0 < Lc; t0 += 16) {
      float u0[16], u1[16], u2[16], rr[16];
      #pragma unroll
      for (int j = 0; j < 16; j++) {
        long o = base0 + (long)(t0 + j) * strideT;
        u0[j] = sU[o];
        u1[j] = sU[o + 1024];
        u2[j] = sU[o + 2048];
        rr[j] = k4 ? sU[o + 3072] : bf2f(sRes16[rbase + (long)(t0 + j) * rstride]);
      }
      #pragma unroll
      for (int j = 0; j < 16; j++) {
        float f = sigmoidf_(u1[j] + vf * c + bfv);
        float r = sigmoidf_(u2[j] + vr * c + brv);
        c = f * c + (1.f - f) * u0[j];
        float h = r * c + (1.f - r) * rr[j];
        long oo = rbase + (long)(t0 + j) * rstride;
        if (sHout) sHout[oo] = h;
        if (sH16) sH16[oo] = f2bf(h);
      }
    }
    cbuf[sid] = c;
    return;
  }
  // ---------------- GEMM part (identical math to k_gemm<0>) ----------------
  const int gb = bid - 64;
  const int ntile = N >> 7;
  const int nwg = (M >> 7) * ntile;
  const int swz = (gb & 7) * (nwg >> 3) + (gb >> 3);
  const int bn = (swz % ntile) * 128, bm = (swz / ntile) * 128;
  const int wave = tid >> 6, lane = tid & 63;
  const int wm = (wave >> 1) * 64, wn = (wave & 1) * 64;
  const int l15 = lane & 15, kq = lane >> 4;
  f32x4 acc[4][4] = {};
  const int r0 = tid >> 3;
  const int c0 = (tid & 7) * 8;
  const unsigned short* Ap = A + (long)(bm + r0) * K + c0;
  const unsigned short* Bp = Bt + (long)(bn + r0) * K + c0;
  for (int kb = 0; kb < K; kb += 64) {
    #pragma unroll
    for (int i = 0; i < 4; i++) {
      gload16(Ap + (long)(i * 32) * K + kb, &As[i * 32 + r0][c0]);
      gload16(Bp + (long)(i * 32) * K + kb, &Bs[i * 32 + r0][c0]);
    }
    __syncthreads();
    #pragma unroll
    for (int kk = 0; kk < 2; kk++) {
      const int kcol = kk * 32 + kq * 8;
      bf16x8 a[4], b[4];
      #pragma unroll
      for (int m = 0; m < 4; m++) a[m] = *(const bf16x8*)&As[wm + m * 16 + l15][kcol];
      #pragma unroll
      for (int n = 0; n < 4; n++) b[n] = *(const bf16x8*)&Bs[wn + n * 16 + l15][kcol];
      #pragma unroll
      for (int m = 0; m < 4; m++)
        #pragma unroll
        for (int n = 0; n < 4; n++)
          acc[m][n] = __builtin_amdgcn_mfma_f32_16x16x32_bf16(a[m], b[n], acc[m][n], 0, 0, 0);
    }
    __syncthreads();
  }
  #pragma unroll
  for (int m = 0; m < 4; m++)
    #pragma unroll
    for (int n = 0; n < 4; n++)
      #pragma unroll
      for (int r = 0; r < 4; r++) {
        int gm = bm + wm + m * 16 + kq * 4 + r;
        int gn = bn + wn + n * 16 + l15;
        Cout[(long)gm * N + gn] = acc[m][n][r];
      }
}

// ---------- SRU scan, standalone (tail chunks) ----------
__global__ __launch_bounds__(64) void k_scan(const float* __restrict__ U,
                                             const unsigned short* __restrict__ Res16,
                                             const float* __restrict__ vc,
                                             const float* __restrict__ bias,
                                             float* __restrict__ Hout,
                                             unsigned short* __restrict__ H16,
                                             float* __restrict__ cbuf,
                                             int Lc, int k4, int first) {
  int tid = blockIdx.x * 64 + threadIdx.x;
  int b = tid >> 10, hc = tid & 1023;
  float vf = vc[hc], vr = vc[1024 + hc];
  float bfv = bias[hc], brv = bias[1024 + hc];
  const int k = k4 ? 4 : 3;
  const long strideT = 16L * k * 1024;
  const long base0 = (long)b * k * 1024 + hc;
  const long rbase = (long)b * 1024 + hc;
  const long rstride = 16 * 1024;
  float c = first ? 0.f : cbuf[tid];
  for (int t0 = 0; t0 < Lc; t0 += 16) {
    float u0[16], u1[16], u2[16], rr[16];
    #pragma unroll
    for (int j = 0; j < 16; j++) {
      long o = base0 + (long)(t0 + j) * strideT;
      u0[j] = U[o];
      u1[j] = U[o + 1024];
      u2[j] = U[o + 2048];
      rr[j] = k4 ? U[o + 3072] : bf2f(Res16[rbase + (long)(t0 + j) * rstride]);
    }
    #pragma unroll
    for (int j = 0; j < 16; j++) {
      float f = sigmoidf_(u1[j] + vf * c + bfv);
      float r = sigmoidf_(u2[j] + vr * c + brv);
      c = f * c + (1.f - f) * u0[j];
      float h = r * c + (1.f - r) * rr[j];
      long oo = rbase + (long)(t0 + j) * rstride;
      if (Hout) Hout[oo] = h;
      if (H16) H16[oo] = f2bf(h);
    }
  }
  cbuf[tid] = c;
}

// ---------- LSTM single step (R6-proven) ----------
__global__ __launch_bounds__(256) void k_lstm_step(
    const unsigned short* __restrict__ Whhb, // (4096,1024) bf16
    const float* __restrict__ Prep,          // (16,4096) fp32 for this t
    const unsigned short* __restrict__ hin,  // (16,1024) bf16
    unsigned short* __restrict__ hout,       // (16,1024) bf16
    float* __restrict__ cst,                 // (16,1024) fp32
    float* __restrict__ HsOutp) {            // (16,1024) fp32 for this t
  const int tid = threadIdx.x;
  const int wave = tid >> 6, lane = tid & 63;
  const int j = blockIdx.x;
  const int c0 = j * 4;
  const int l15 = lane & 15, kq = lane >> 4;
  const int wrow = (l15 >> 2) * 1024 + c0 + (l15 & 3);
  const int pm = tid >> 4, pcol = tid & 15;
  float pre = Prep[(long)pm * 4096 + (pcol >> 2) * 1024 + c0 + (pcol & 3)];
  float cold = 0.f;
  long ci = 0;
  if (tid < 64) {
    int m = tid & 15, chl = tid >> 4;
    ci = (long)m * 1024 + c0 + chl;
    cold = cst[ci];
  }
  f32x4 acc = {0.f, 0.f, 0.f, 0.f};
  const unsigned short* hp = hin + l15 * 1024 + wave * 256 + kq * 8;
  const unsigned short* wp = Whhb + (long)wrow * 1024 + wave * 256 + kq * 8;
  #pragma unroll
  for (int kb = 0; kb < 256; kb += 32) {
    bf16x8 a = *(const bf16x8*)(hp + kb);
    bf16x8 w = *(const bf16x8*)(wp + kb);
    acc = __builtin_amdgcn_mfma_f32_16x16x32_bf16(a, w, acc, 0, 0, 0);
  }
  __shared__ float P[4][16][16];
  __shared__ float G[16][16];
  #pragma unroll
  for (int r = 0; r < 4; r++) {
    int m = kq * 4 + r;
    P[wave][m][l15] = acc[r];
  }
  __syncthreads();
  G[pm][pcol] = P[0][pm][pcol] + P[1][pm][pcol] + P[2][pm][pcol] + P[3][pm][pcol] + pre;
  __syncthreads();
  if (tid < 64) {
    int m = tid & 15, chl = tid >> 4;
    float ig = G[m][0 * 4 + chl];
    float fg = G[m][1 * 4 + chl];
    float gg = G[m][2 * 4 + chl];
    float og = G[m][3 * 4 + chl];
    float cn = sigmoidf_(fg) * cold + sigmoidf_(ig) * tanhf_(gg);
    float hn = sigmoidf_(og) * tanhf_(cn);
    cst[ci] = cn;
    hout[ci] = f2bf(hn);
    HsOutp[ci] = hn;
  }
}

// ---------- host ----------

extern "C" void kernel_launch(void* const* d_in, const int* in_sizes, int n_in,
                              void* d_out, int out_size, void* d_ws, size_t ws_size,
                              hipStream_t stream) {
  const float* x    = (const float*)d_in[0];
  const float* w0   = (const float*)d_in[1];
  const float* vc0  = (const float*)d_in[2];
  const float* b0   = (const float*)d_in[3];
  const float* g0   = (const float*)d_in[4];
  const float* be0  = (const float*)d_in[5];
  const float* Ws   = (const float*)d_in[6];
  const float* VCs  = (const float*)d_in[7];
  const float* Bsi  = (const float*)d_in[8];
  const float* Gs   = (const float*)d_in[9];
  const float* Bes  = (const float*)d_in[10];
  const float* Wih  = (const float*)d_in[11];
  const float* Whh  = (const float*)d_in[12];
  const float* bih  = (const float*)d_in[13];
  const float* bhh  = (const float*)d_in[14];
  const float* gh   = (const float*)d_in[15];
  const float* bh   = (const float*)d_in[16];
  const float* Wout = (const float*)d_in[17];

  char* ws = (char*)d_ws;
  size_t off = 0;
  auto alloc = [&](size_t bytes) {
    size_t r = off;
    off += (bytes + 255) & ~(size_t)255;
    return r;
  };
  unsigned short* W0t   = (unsigned short*)(ws + alloc(4096UL * 128 * 2));      //  1 MB
  unsigned short* Wst   = (unsigned short*)(ws + alloc(6UL * 3072 * 1024 * 2)); // 36 MB
  unsigned short* Wihb  = (unsigned short*)(ws + alloc(4096UL * 1024 * 2));     //  8 MB
  unsigned short* Whhb  = (unsigned short*)(ws + alloc(4096UL * 1024 * 2));     //  8 MB
  unsigned short* Woutt = (unsigned short*)(ws + alloc(1024UL * 1024 * 2));     //  2 MB
  unsigned short* Xn    = (unsigned short*)(ws + alloc(16384UL * 1024 * 2));    // 32 MB
  float*          Hbuf  = (float*)(ws + alloc(16384UL * 1024 * 4));             // 64 MB
  float*          Ubuf  = (float*)(ws + alloc(2UL * 4096 * 3072 * 4));          // 96 MB (2 halves)
  unsigned short* hb0   = (unsigned short*)(ws + alloc(16UL * 1024 * 2));
  unsigned short* hb1   = (unsigned short*)(ws + alloc(16UL * 1024 * 2));
  float*          cst   = (float*)(ws + alloc(16UL * 1024 * 4));
  float*          cscan = (float*)(ws + alloc(16UL * 1024 * 4));
  const long U_HALF = 4096L * 3072;          // floats per Ubuf half (48 MB)
  // aliases (lifetimes do not overlap):
  float*          HsOut = Hbuf;              // (512,16,1024) fp32 during LSTM
  unsigned short* H16l6 = Xn + 8192L * 1024; // layer-6 h bf16 (8192 rows)
  unsigned short* LNout = Xn;                // final LN bf16 out (8192 rows)

  // ---- weight conversion ----
  k_cast_t<<<dim3(4096 / 32, 128 / 32), dim3(32, 8), 0, stream>>>(w0, W0t, 128, 4096);
  for (int i = 0; i < 6; i++)
    k_cast_t<<<dim3(3072 / 32, 1024 / 32), dim3(32, 8), 0, stream>>>(
        Ws + (long)i * 1024 * 3072, Wst + (long)i * 3072 * 1024, 1024, 3072);
  k_cast_t<<<dim3(1024 / 32, 1024 / 32), dim3(32, 8), 0, stream>>>(Wout, Woutt, 1024, 1001);
  k_castf<<<4096, 256, 0, stream>>>(Wih, Wihb, 4096 * 1024 / 4);
  k_castf<<<4096, 256, 0, stream>>>(Whh, Whhb, 4096 * 1024 / 4);
  hipMemsetAsync(hb0, 0, 32768 + 32768 + 65536, stream); // hb0, hb1, cst contiguous

  // ---- SRU layer 0 (k=4, K=128), CH_T=128, fused GEMM||scan pipeline ----
  {
    const int T0 = 128, R0 = T0 * 16; // 2048 rows/chunk, 8 chunks
    k_ln0<<<16384, 128, 0, stream>>>(x, Xn, g0, be0);
    for (int c = 0; c < 8; c++) {
      float* Uc = Ubuf + (c & 1) * U_HALF;
      if (c == 0) {
        k_gemm<0><<<dim3(4096 / 128, R0 / 128), 256, 0, stream>>>(
            Xn, W0t, Uc, nullptr, nullptr, R0, 4096, 128);
      } else {
        k_gemm_scan<<<64 + (4096 / 128) * (R0 / 128), 256, 0, stream>>>(
            Xn + (long)c * R0 * 128, W0t, Uc, R0, 4096, 128,
            Ubuf + ((c - 1) & 1) * U_HALF, nullptr, vc0, b0,
            Hbuf + (long)(c - 1) * R0 * 1024, nullptr, cscan, T0, 1, c == 1);
      }
    }
    k_scan<<<256, 64, 0, stream>>>(Ubuf + (7 & 1) * U_HALF, nullptr, vc0, b0,
                                   Hbuf + 7L * R0 * 1024, nullptr, cscan, T0, 1, 0);
  }

  // ---- SRU layers 1..6 (k=3, K=1024), CH_T=256, fused pipeline ----
  const int CH_T = 256, CH_R = CH_T * 16; // 4096 rows/chunk
  for (int i = 0; i < 6; i++) {
    int L = (i < 3) ? 1024 : 512;
    int rows = L * 16;
    int avg = (i == 3) ? 1 : 0;
    k_ln<<<rows, 256, 0, stream>>>(Hbuf, Xn, Gs + i * 1024, Bes + i * 1024, avg);
    int nch = rows / CH_R; // 4 or 2
    const unsigned short* Wb = Wst + (long)i * 3072 * 1024;
    for (int c = 0; c < nch; c++) {
      float* Uc = Ubuf + (c & 1) * U_HALF;
      if (c == 0) {
        k_gemm<0><<<dim3(3072 / 128, CH_R / 128), 256, 0, stream>>>(
            Xn, Wb, Uc, nullptr, nullptr, CH_R, 3072, 1024);
      } else {
        int sc = c - 1;
        k_gemm_scan<<<64 + (3072 / 128) * (CH_R / 128), 256, 0, stream>>>(
            Xn + (long)c * CH_R * 1024, Wb, Uc, CH_R, 3072, 1024,
            Ubuf + (sc & 1) * U_HALF, Xn + (long)sc * CH_R * 1024,
            VCs + i * 2048, Bsi + i * 2048,
            (i == 5) ? nullptr : (Hbuf + (long)sc * CH_R * 1024),
            (i == 5) ? (H16l6 + (long)sc * CH_R * 1024) : nullptr,
            cscan, CH_T, 0, sc == 0);
      }
    }
    int sc = nch - 1;
    k_scan<<<256, 64, 0, stream>>>(Ubuf + (sc & 1) * U_HALF,
                                   Xn + (long)sc * CH_R * 1024,
                                   VCs + i * 2048, Bsi + i * 2048,
                                   (i == 5) ? nullptr : (Hbuf + (long)sc * CH_R * 1024),
                                   (i == 5) ? (H16l6 + (long)sc * CH_R * 1024) : nullptr,
                                   cscan, CH_T, 0, sc == 0);
  }

  // ---- LSTM: chunked input projection + 512 step kernels ----
  // (HsOut aliases Hbuf; Ubuf used as one 64 MB buffer -- scans are done)
  const int LCH_T = 256, LCH_R = LCH_T * 16; // 4096 rows per chunk
  for (int c = 0; c < 2; c++) {
    k_gemm<1><<<dim3(4096 / 128, LCH_R / 128), 256, 0, stream>>>(
        H16l6 + (long)c * LCH_R * 1024, Wihb, Ubuf, bih, bhh, LCH_R, 4096, 1024);
    for (int tl = 0; tl < LCH_T; tl++) {
      int tg = c * LCH_T + tl;
      unsigned short* hin = (tg & 1) ? hb1 : hb0;
      unsigned short* hout = (tg & 1) ? hb0 : hb1;
      k_lstm_step<<<256, 256, 0, stream>>>(Whhb, Ubuf + (long)tl * 16 * 4096, hin, hout,
                                           cst, HsOut + (long)tg * 16 * 1024);
    }
  }

  // ---- final LN + output projection ----
  k_ln<<<8192, 256, 0, stream>>>(HsOut, LNout, gh, bh, 0);
  k_gemm<2><<<dim3(1024 / 128, 8192 / 128), 256, 0, stream>>>(LNout, Woutt, d_out, nullptr,
                                                              nullptr, 8192, 1024, 1024);
}